// Round 2
// baseline (1110.140 us; speedup 1.0000x reference)
//
#include <hip/hip_runtime.h>
#include <hip/hip_bf16.h>

#define B_      2
#define S_      1024
#define HID     4096
#define NH      32
#define NKV     8
#define D_      128
#define G_      4
#define WINDOW  512
#define QKV_OUT 6144      // (NH + 2*NKV) * D
#define M_TOT   2048      // B * S

typedef __bf16 bf16x8 __attribute__((ext_vector_type(8)));
typedef float  f32x4  __attribute__((ext_vector_type(4)));
typedef unsigned short u16x8 __attribute__((ext_vector_type(8)));

static __device__ __forceinline__ float bf2f(unsigned short u) {
    union { unsigned int i; float f; } v; v.i = ((unsigned int)u) << 16; return v.f;
}
static __device__ __forceinline__ unsigned short f2bf(float f) {
    union { float f; unsigned int i; } v; v.f = f;
    unsigned int x = v.i;
    return (unsigned short)((x + 0x7fffu + ((x >> 16) & 1u)) >> 16);
}

// C[M][N] = A[M][K] * Bw[N][K]^T + bias[N].
// A: fp32 or bf16 (A_BF16). Bw, bias: fp32. C: fp32 or bf16 (C_BF16).
// Internally bf16 MFMA (RTNE casts at staging), fp32 accum.
// 128x128 block tile, BK=32, 4 waves in 2x2, each wave 4x4 tiles of 16x16x32 MFMA.
template<bool A_BF16, bool C_BF16>
__global__ __launch_bounds__(256)
void gemm_bt_bias(const void* __restrict__ Av,
                  const float* __restrict__ Bw,
                  const float* __restrict__ bias,
                  void* __restrict__ Cv,
                  int M, int N, int K)
{
    // rows padded to 40 elems (80 B = 5*16B: keeps 16B alignment, breaks pow2 bank stride)
    __shared__ unsigned short As[128 * 40];
    __shared__ unsigned short Bs[128 * 40];

    const int tid  = threadIdx.x;
    const int m0   = blockIdx.y * 128;
    const int n0   = blockIdx.x * 128;
    const int wave = tid >> 6, lane = tid & 63;
    const int wm   = (wave >> 1) * 64;
    const int wn   = (wave & 1) * 64;
    const int lm   = lane & 15, quad = lane >> 4;

    f32x4 acc[4][4] = {};

    for (int k0 = 0; k0 < K; k0 += 32) {
        __syncthreads();
        #pragma unroll
        for (int c = 0; c < 2; ++c) {
            int chunk = tid + c * 256;           // 0..511
            int row   = chunk >> 2;              // 0..127
            int off   = (chunk & 3) * 8;         // 0,8,16,24

            // A tile
            if (A_BF16) {
                *(u16x8*)&As[row * 40 + off] =
                    *(const u16x8*)&((const unsigned short*)Av)[(size_t)(m0 + row) * K + k0 + off];
            } else {
                const float* ap = &((const float*)Av)[(size_t)(m0 + row) * K + k0 + off];
                float4 f0 = *(const float4*)ap;
                float4 f1 = *(const float4*)(ap + 4);
                u16x8 h;
                h[0]=f2bf(f0.x); h[1]=f2bf(f0.y); h[2]=f2bf(f0.z); h[3]=f2bf(f0.w);
                h[4]=f2bf(f1.x); h[5]=f2bf(f1.y); h[6]=f2bf(f1.z); h[7]=f2bf(f1.w);
                *(u16x8*)&As[row * 40 + off] = h;
            }
            // B tile (always fp32 weights)
            {
                const float* bp = &Bw[(size_t)(n0 + row) * K + k0 + off];
                float4 f0 = *(const float4*)bp;
                float4 f1 = *(const float4*)(bp + 4);
                u16x8 h;
                h[0]=f2bf(f0.x); h[1]=f2bf(f0.y); h[2]=f2bf(f0.z); h[3]=f2bf(f0.w);
                h[4]=f2bf(f1.x); h[5]=f2bf(f1.y); h[6]=f2bf(f1.z); h[7]=f2bf(f1.w);
                *(u16x8*)&Bs[row * 40 + off] = h;
            }
        }
        __syncthreads();

        bf16x8 afr[4], bfr[4];
        #pragma unroll
        for (int i = 0; i < 4; ++i)
            afr[i] = *(const bf16x8*)&As[(wm + i * 16 + lm) * 40 + quad * 8];
        #pragma unroll
        for (int j = 0; j < 4; ++j)
            bfr[j] = *(const bf16x8*)&Bs[(wn + j * 16 + lm) * 40 + quad * 8];

        #pragma unroll
        for (int i = 0; i < 4; ++i)
            #pragma unroll
            for (int j = 0; j < 4; ++j)
                acc[i][j] = __builtin_amdgcn_mfma_f32_16x16x32_bf16(afr[i], bfr[j], acc[i][j], 0, 0, 0);
    }

    #pragma unroll
    for (int j = 0; j < 4; ++j) {
        int col = n0 + wn + j * 16 + lm;
        float bv = bias[col];
        #pragma unroll
        for (int i = 0; i < 4; ++i) {
            int rowb = m0 + wm + i * 16 + quad * 4;
            #pragma unroll
            for (int r = 0; r < 4; ++r) {
                float val = acc[i][j][r] + bv;
                if (C_BF16)
                    ((unsigned short*)Cv)[(size_t)(rowb + r) * N + col] = f2bf(val);
                else
                    ((float*)Cv)[(size_t)(rowb + r) * N + col] = val;
            }
        }
    }
}

// In-place RoPE on q heads (o in [0,4096)) and k heads (o in [4096,5120)); qkv bf16, cos/sin fp32.
__global__ __launch_bounds__(256)
void rope_kernel(unsigned short* __restrict__ qkv,
                 const float* __restrict__ cosb,
                 const float* __restrict__ sinb)
{
    int t    = blockIdx.x * 256 + threadIdx.x;   // 2048*40*64 total, exact
    int d    = t & 63;
    int rest = t >> 6;
    int head = rest % 40;
    int m    = rest / 40;          // 0..2047
    int s    = m & (S_ - 1);
    int obase = (head < NH) ? head * D_ : HID + (head - NH) * D_;
    size_t base = (size_t)m * QKV_OUT + obase;

    float x1 = bf2f(qkv[base + d]);
    float x2 = bf2f(qkv[base + d + 64]);
    float c1 = cosb[s * D_ + d];
    float s1 = sinb[s * D_ + d];
    float c2 = cosb[s * D_ + d + 64];
    float s2 = sinb[s * D_ + d + 64];
    qkv[base + d]      = f2bf(x1 * c1 - x2 * s1);
    qkv[base + d + 64] = f2bf(x2 * c2 + x1 * s2);
}

// Attention: block = (b, h, 16-row q-tile). Scores for the tile's key window
// (<=527 cols) materialized in LDS; exact two-pass softmax; VALU PV.
#define QT 16
#define SW 545   // score row stride in floats (545 % 32 == 17: no pow2 bank stride)
__global__ __launch_bounds__(256)
void attn_kernel(const unsigned short* __restrict__ qkv,
                 unsigned short* __restrict__ attn)
{
    __shared__ float Q[QT * 132];
    __shared__ float Sc[QT * SW];
    __shared__ float invl[QT];

    const int tid = threadIdx.x;
    const int qt  = blockIdx.x;          // 0..63
    const int h   = blockIdx.y;          // 0..31
    const int b   = blockIdx.z;          // 0..1
    const int kvh = h >> 2;              // G = 4
    const int r0  = qt * QT;
    const int jmin = max(0, r0 - (WINDOW - 1));
    const int jmax = r0 + QT - 1;
    const int JT   = jmax - jmin + 1;    // <= 527

    const size_t qkv_b = (size_t)b * S_ * QKV_OUT;
    const float scale = 0.08838834764831845f;   // 1/sqrt(128)

    for (int idx = tid; idx < QT * D_; idx += 256) {
        int r = idx >> 7, d = idx & 127;
        Q[r * 132 + d] = bf2f(qkv[qkv_b + (size_t)(r0 + r) * QKV_OUT + h * D_ + d]) * scale;
    }
    __syncthreads();

    // phase 1: scores (consecutive tids share j -> K loads broadcast; Q rows spread banks)
    for (int idx = tid; idx < QT * JT; idx += 256) {
        int r  = idx & 15;
        int jj = idx >> 4;
        int j  = jmin + jj;
        int sg = r0 + r;
        float val = -1e30f;
        if (j <= sg && (sg - j) < WINDOW) {
            const unsigned short* kptr = &qkv[qkv_b + (size_t)j * QKV_OUT + HID + kvh * D_];
            float dot = 0.f;
            #pragma unroll 4
            for (int d8 = 0; d8 < D_; d8 += 8) {
                u16x8 k8 = *(const u16x8*)&kptr[d8];
                float4 qa = *(const float4*)&Q[r * 132 + d8];
                float4 qb = *(const float4*)&Q[r * 132 + d8 + 4];
                dot += qa.x * bf2f(k8[0]) + qa.y * bf2f(k8[1]) + qa.z * bf2f(k8[2]) + qa.w * bf2f(k8[3]);
                dot += qb.x * bf2f(k8[4]) + qb.y * bf2f(k8[5]) + qb.z * bf2f(k8[6]) + qb.w * bf2f(k8[7]);
            }
            val = dot;
        }
        Sc[r * SW + jj] = val;
    }
    __syncthreads();

    // phase 2: softmax, one 16-lane group per row (xor<16 stays inside the group)
    {
        int r  = tid >> 4;
        int li = tid & 15;
        float mx = -3.0e38f;
        for (int jj = li; jj < JT; jj += 16) mx = fmaxf(mx, Sc[r * SW + jj]);
        #pragma unroll
        for (int o = 8; o >= 1; o >>= 1) mx = fmaxf(mx, __shfl_xor(mx, o, 64));
        float sum = 0.f;
        for (int jj = li; jj < JT; jj += 16) {
            float e = __expf(Sc[r * SW + jj] - mx);
            Sc[r * SW + jj] = e;
            sum += e;
        }
        #pragma unroll
        for (int o = 8; o >= 1; o >>= 1) sum += __shfl_xor(sum, o, 64);
        if (li == 0) invl[r] = 1.0f / sum;
    }
    __syncthreads();

    // phase 3: PV; thread owns (row r, 8 output dims), V loads coalesced per 16-lane group
    {
        int r  = tid >> 4;
        int d0 = (tid & 15) * 8;
        float o8[8] = {};
        const unsigned short* vbase = &qkv[qkv_b + HID + NKV * D_ + kvh * D_ + d0];
        for (int jj = 0; jj < JT; ++jj) {
            float p = Sc[r * SW + jj];
            u16x8 v8 = *(const u16x8*)&vbase[(size_t)(jmin + jj) * QKV_OUT];
            #pragma unroll
            for (int e = 0; e < 8; ++e) o8[e] += p * bf2f(v8[e]);
        }
        float il = invl[r];
        u16x8 out8;
        #pragma unroll
        for (int e = 0; e < 8; ++e) out8[e] = f2bf(o8[e] * il);
        *(u16x8*)&attn[(size_t)(b * S_ + r0 + r) * (NH * D_) + h * D_ + d0] = out8;
    }
}

extern "C" void kernel_launch(void* const* d_in, const int* in_sizes, int n_in,
                              void* d_out, int out_size, void* d_ws, size_t ws_size,
                              hipStream_t stream)
{
    const float* hidden = (const float*)d_in[0];
    const float* cosb   = (const float*)d_in[1];
    const float* sinb   = (const float*)d_in[2];
    const float* w_qkv  = (const float*)d_in[3];
    const float* b_qkv  = (const float*)d_in[4];
    const float* w_o    = (const float*)d_in[5];
    const float* b_o    = (const float*)d_in[6];
    float* out = (float*)d_out;

    unsigned short* qkv_ws  = (unsigned short*)d_ws;                 // 2048 x 6144 bf16
    unsigned short* attn_ws = qkv_ws + (size_t)M_TOT * QKV_OUT;      // 2048 x 4096 bf16

    dim3 blk(256);
    gemm_bt_bias<false, true><<<dim3(QKV_OUT / 128, M_TOT / 128), blk, 0, stream>>>(
        hidden, w_qkv, b_qkv, qkv_ws, M_TOT, QKV_OUT, HID);
    rope_kernel<<<dim3((M_TOT * 40 * 64) / 256), blk, 0, stream>>>(qkv_ws, cosb, sinb);
    attn_kernel<<<dim3(S_ / QT, NH, B_), blk, 0, stream>>>(qkv_ws, attn_ws);
    gemm_bt_bias<true, false><<<dim3(HID / 128, M_TOT / 128), blk, 0, stream>>>(
        attn_ws, w_o, b_o, out, M_TOT, HID, NH * D_);
}

// Round 3
// 639.325 us; speedup vs baseline: 1.7364x; 1.7364x over previous
//
#include <hip/hip_runtime.h>
#include <hip/hip_bf16.h>

#define B_      2
#define S_      1024
#define HID     4096
#define NH      32
#define NKV     8
#define D_      128
#define G_      4
#define WINDOW  512
#define QKV_OUT 6144      // (NH + 2*NKV) * D
#define M_TOT   2048      // B * S
#define CH      32        // kv chunk length in attention

typedef __bf16 bf16x8 __attribute__((ext_vector_type(8)));
typedef float  f32x4  __attribute__((ext_vector_type(4)));
typedef unsigned short u16x8 __attribute__((ext_vector_type(8)));

static __device__ __forceinline__ float bf2f(unsigned short u) {
    union { unsigned int i; float f; } v; v.i = ((unsigned int)u) << 16; return v.f;
}
static __device__ __forceinline__ unsigned short f2bf(float f) {
    union { float f; unsigned int i; } v; v.f = f;
    unsigned int x = v.i;
    return (unsigned short)((x + 0x7fffu + ((x >> 16) & 1u)) >> 16);
}

// C[M][N] = A[M][K] * Bw[N][K]^T + bias[N].
// A: fp32 or bf16 (A_BF16). Bw, bias: fp32. C: fp32 or bf16 (C_BF16).
// Internally bf16 MFMA (RTNE casts at staging), fp32 accum.
template<bool A_BF16, bool C_BF16>
__global__ __launch_bounds__(256)
void gemm_bt_bias(const void* __restrict__ Av,
                  const float* __restrict__ Bw,
                  const float* __restrict__ bias,
                  void* __restrict__ Cv,
                  int M, int N, int K)
{
    __shared__ unsigned short As[128 * 40];
    __shared__ unsigned short Bs[128 * 40];

    const int tid  = threadIdx.x;
    const int m0   = blockIdx.y * 128;
    const int n0   = blockIdx.x * 128;
    const int wave = tid >> 6, lane = tid & 63;
    const int wm   = (wave >> 1) * 64;
    const int wn   = (wave & 1) * 64;
    const int lm   = lane & 15, quad = lane >> 4;

    f32x4 acc[4][4] = {};

    for (int k0 = 0; k0 < K; k0 += 32) {
        __syncthreads();
        #pragma unroll
        for (int c = 0; c < 2; ++c) {
            int chunk = tid + c * 256;
            int row   = chunk >> 2;
            int off   = (chunk & 3) * 8;

            if (A_BF16) {
                *(u16x8*)&As[row * 40 + off] =
                    *(const u16x8*)&((const unsigned short*)Av)[(size_t)(m0 + row) * K + k0 + off];
            } else {
                const float* ap = &((const float*)Av)[(size_t)(m0 + row) * K + k0 + off];
                float4 f0 = *(const float4*)ap;
                float4 f1 = *(const float4*)(ap + 4);
                u16x8 h;
                h[0]=f2bf(f0.x); h[1]=f2bf(f0.y); h[2]=f2bf(f0.z); h[3]=f2bf(f0.w);
                h[4]=f2bf(f1.x); h[5]=f2bf(f1.y); h[6]=f2bf(f1.z); h[7]=f2bf(f1.w);
                *(u16x8*)&As[row * 40 + off] = h;
            }
            {
                const float* bp = &Bw[(size_t)(n0 + row) * K + k0 + off];
                float4 f0 = *(const float4*)bp;
                float4 f1 = *(const float4*)(bp + 4);
                u16x8 h;
                h[0]=f2bf(f0.x); h[1]=f2bf(f0.y); h[2]=f2bf(f0.z); h[3]=f2bf(f0.w);
                h[4]=f2bf(f1.x); h[5]=f2bf(f1.y); h[6]=f2bf(f1.z); h[7]=f2bf(f1.w);
                *(u16x8*)&Bs[row * 40 + off] = h;
            }
        }
        __syncthreads();

        bf16x8 afr[4], bfr[4];
        #pragma unroll
        for (int i = 0; i < 4; ++i)
            afr[i] = *(const bf16x8*)&As[(wm + i * 16 + lm) * 40 + quad * 8];
        #pragma unroll
        for (int j = 0; j < 4; ++j)
            bfr[j] = *(const bf16x8*)&Bs[(wn + j * 16 + lm) * 40 + quad * 8];

        #pragma unroll
        for (int i = 0; i < 4; ++i)
            #pragma unroll
            for (int j = 0; j < 4; ++j)
                acc[i][j] = __builtin_amdgcn_mfma_f32_16x16x32_bf16(afr[i], bfr[j], acc[i][j], 0, 0, 0);
    }

    #pragma unroll
    for (int j = 0; j < 4; ++j) {
        int col = n0 + wn + j * 16 + lm;
        float bv = bias[col];
        #pragma unroll
        for (int i = 0; i < 4; ++i) {
            int rowb = m0 + wm + i * 16 + quad * 4;
            #pragma unroll
            for (int r = 0; r < 4; ++r) {
                float val = acc[i][j][r] + bv;
                if (C_BF16)
                    ((unsigned short*)Cv)[(size_t)(rowb + r) * N + col] = f2bf(val);
                else
                    ((float*)Cv)[(size_t)(rowb + r) * N + col] = val;
            }
        }
    }
}

// In-place RoPE on q heads and k heads; qkv bf16, cos/sin fp32.
__global__ __launch_bounds__(256)
void rope_kernel(unsigned short* __restrict__ qkv,
                 const float* __restrict__ cosb,
                 const float* __restrict__ sinb)
{
    int t    = blockIdx.x * 256 + threadIdx.x;
    int d    = t & 63;
    int rest = t >> 6;
    int head = rest % 40;
    int m    = rest / 40;
    int s    = m & (S_ - 1);
    int obase = (head < NH) ? head * D_ : HID + (head - NH) * D_;
    size_t base = (size_t)m * QKV_OUT + obase;

    float x1 = bf2f(qkv[base + d]);
    float x2 = bf2f(qkv[base + d + 64]);
    float c1 = cosb[s * D_ + d];
    float s1 = sinb[s * D_ + d];
    float c2 = cosb[s * D_ + d + 64];
    float s2 = sinb[s * D_ + d + 64];
    qkv[base + d]      = f2bf(x1 * c1 - x2 * s1);
    qkv[base + d + 64] = f2bf(x2 * c2 + x1 * s2);
}

// Flash-style MFMA attention. Block = (b, h, 64 q-rows); 4 waves x 16 q-rows.
// KV chunks of 32 staged in LDS. QK^T and PV on mfma_f32_16x16x32_bf16.
// Online softmax in C-layout (row = quad*4+reg spans the 16 lanes of a quad group).
__global__ __launch_bounds__(256)
void attn_mfma(const unsigned short* __restrict__ qkv,
               unsigned short* __restrict__ attn)
{
    __shared__ unsigned short Kl[CH * 136];
    __shared__ unsigned short Vl[CH * 136];
    __shared__ unsigned short Pl[4][16 * 40];

    const int tid  = threadIdx.x;
    const int wave = tid >> 6, lane = tid & 63;
    const int lm   = lane & 15, quad = lane >> 4;
    const int h    = blockIdx.y;
    const int b    = blockIdx.z;
    const int kvh  = h >> 2;
    const int r0b  = blockIdx.x * 64;
    const int rw0  = r0b + wave * 16;

    const size_t qkv_b = (size_t)b * S_ * QKV_OUT;
    const float SCL = 0.12751974f;   // (1/sqrt(128)) * log2(e)

    // Q A-fragments: lane m = lm, k = quad*8 + j; 4 frags cover D=128
    bf16x8 qf[4];
    {
        const unsigned short* qrow = qkv + qkv_b + (size_t)(rw0 + lm) * QKV_OUT + h * D_ + quad * 8;
        #pragma unroll
        for (int kb = 0; kb < 4; ++kb)
            qf[kb] = *(const bf16x8*)(qrow + kb * 32);
    }

    f32x4 O[8] = {};
    float mrow[4] = {-1e30f, -1e30f, -1e30f, -1e30f};
    float lrow[4] = {0.f, 0.f, 0.f, 0.f};

    const int c0   = max(0, r0b - (WINDOW - 1)) & ~(CH - 1);
    const int cend = r0b + 64 - CH;   // last chunk start covering row r0b+63

    for (int c = c0; c <= cend + CH; c += CH) {
        if (c > cend) break;
        __syncthreads();
        // stage K and V chunk rows c..c+31 (coalesced 16B per lane)
        #pragma unroll
        for (int p = 0; p < 2; ++p) {
            int idx = tid + p * 256;
            int row = idx >> 4;
            int d0  = (idx & 15) * 8;
            const unsigned short* kg = qkv + qkv_b + (size_t)(c + row) * QKV_OUT + HID + kvh * D_ + d0;
            *(u16x8*)&Kl[row * 136 + d0] = *(const u16x8*)kg;
            *(u16x8*)&Vl[row * 136 + d0] = *(const u16x8*)(kg + NKV * D_);
        }
        __syncthreads();

        // wave-uniform skip: chunk outside this wave's window
        if (c + CH - 1 < rw0 - (WINDOW - 1) || c > rw0 + 15) continue;

        // QK^T: two 16-col tiles
        f32x4 s0 = {}, s1 = {};
        #pragma unroll
        for (int kb = 0; kb < 4; ++kb) {
            bf16x8 b0 = *(const bf16x8*)&Kl[lm * 136 + kb * 32 + quad * 8];
            bf16x8 b1 = *(const bf16x8*)&Kl[(16 + lm) * 136 + kb * 32 + quad * 8];
            s0 = __builtin_amdgcn_mfma_f32_16x16x32_bf16(qf[kb], b0, s0, 0, 0, 0);
            s1 = __builtin_amdgcn_mfma_f32_16x16x32_bf16(qf[kb], b1, s1, 0, 0, 0);
        }

        // online softmax per row (C layout: row = quad*4+reg, col = lm)
        const int j0 = c + lm, j1 = c + 16 + lm;
        float alpha[4];
        #pragma unroll
        for (int r = 0; r < 4; ++r) {
            int row = rw0 + quad * 4 + r;
            float t0 = (j0 <= row && row - j0 < WINDOW) ? s0[r] : -3.0e38f;
            float t1 = (j1 <= row && row - j1 < WINDOW) ? s1[r] : -3.0e38f;
            float cm = fmaxf(t0, t1);
            #pragma unroll
            for (int o = 8; o >= 1; o >>= 1) cm = fmaxf(cm, __shfl_xor(cm, o, 16));
            float mnew = fmaxf(mrow[r], cm);
            float al   = exp2f((mrow[r] - mnew) * SCL);
            float p0   = exp2f((t0 - mnew) * SCL);
            float p1   = exp2f((t1 - mnew) * SCL);
            float rs   = p0 + p1;
            #pragma unroll
            for (int o = 8; o >= 1; o >>= 1) rs += __shfl_xor(rs, o, 16);
            mrow[r] = mnew;
            lrow[r] = lrow[r] * al + rs;
            alpha[r] = al;
            Pl[wave][(quad * 4 + r) * 40 + lm]      = f2bf(p0);
            Pl[wave][(quad * 4 + r) * 40 + 16 + lm] = f2bf(p1);
        }

        // rescale O
        #pragma unroll
        for (int nt = 0; nt < 8; ++nt)
            #pragma unroll
            for (int r = 0; r < 4; ++r)
                O[nt][r] *= alpha[r];

        // PV: A = P (from per-wave LDS, wave-internal RAW), B = V gathered
        bf16x8 pa = *(const bf16x8*)&Pl[wave][lm * 40 + quad * 8];
        #pragma unroll
        for (int nt = 0; nt < 8; ++nt) {
            u16x8 vb;
            #pragma unroll
            for (int j = 0; j < 8; ++j)
                vb[j] = Vl[(quad * 8 + j) * 136 + nt * 16 + lm];
            O[nt] = __builtin_amdgcn_mfma_f32_16x16x32_bf16(pa, *(bf16x8*)&vb, O[nt], 0, 0, 0);
        }
    }

    // epilogue: O / l, store bf16
    float il[4];
    #pragma unroll
    for (int r = 0; r < 4; ++r) il[r] = 1.0f / lrow[r];
    #pragma unroll
    for (int nt = 0; nt < 8; ++nt)
        #pragma unroll
        for (int r = 0; r < 4; ++r) {
            int row = rw0 + quad * 4 + r;
            attn[(size_t)(b * S_ + row) * (NH * D_) + h * D_ + nt * 16 + lm] = f2bf(O[nt][r] * il[r]);
        }
}

extern "C" void kernel_launch(void* const* d_in, const int* in_sizes, int n_in,
                              void* d_out, int out_size, void* d_ws, size_t ws_size,
                              hipStream_t stream)
{
    const float* hidden = (const float*)d_in[0];
    const float* cosb   = (const float*)d_in[1];
    const float* sinb   = (const float*)d_in[2];
    const float* w_qkv  = (const float*)d_in[3];
    const float* b_qkv  = (const float*)d_in[4];
    const float* w_o    = (const float*)d_in[5];
    const float* b_o    = (const float*)d_in[6];
    float* out = (float*)d_out;

    unsigned short* qkv_ws  = (unsigned short*)d_ws;                 // 2048 x 6144 bf16
    unsigned short* attn_ws = qkv_ws + (size_t)M_TOT * QKV_OUT;      // 2048 x 4096 bf16

    dim3 blk(256);
    gemm_bt_bias<false, true><<<dim3(QKV_OUT / 128, M_TOT / 128), blk, 0, stream>>>(
        hidden, w_qkv, b_qkv, qkv_ws, M_TOT, QKV_OUT, HID);
    rope_kernel<<<dim3((M_TOT * 40 * 64) / 256), blk, 0, stream>>>(qkv_ws, cosb, sinb);
    attn_mfma<<<dim3(S_ / 64, NH, B_), blk, 0, stream>>>(qkv_ws, attn_ws);
    gemm_bt_bias<true, false><<<dim3(HID / 128, M_TOT / 128), blk, 0, stream>>>(
        attn_ws, w_o, b_o, out, M_TOT, HID, NH * D_);
}

// Round 4
// 547.156 us; speedup vs baseline: 2.0289x; 1.1685x over previous
//
#include <hip/hip_runtime.h>
#include <hip/hip_bf16.h>

#define B_      2
#define S_      1024
#define HID     4096
#define NH      32
#define NKV     8
#define D_      128
#define G_      4
#define WINDOW  512
#define QKV_OUT 6144      // (NH + 2*NKV) * D
#define M_TOT   2048      // B * S
#define CH      32        // kv chunk length in attention
#define VSTR    40        // transposed-V row stride (80 B: 16B-aligned frags, 2-way banks)

typedef __bf16 bf16x8 __attribute__((ext_vector_type(8)));
typedef float  f32x4  __attribute__((ext_vector_type(4)));
typedef unsigned short u16x8 __attribute__((ext_vector_type(8)));

#define AS1 __attribute__((address_space(1)))
#define AS3 __attribute__((address_space(3)))

static __device__ __forceinline__ float bf2f(unsigned short u) {
    union { unsigned int i; float f; } v; v.i = ((unsigned int)u) << 16; return v.f;
}
static __device__ __forceinline__ unsigned short f2bf(float f) {
    union { float f; unsigned int i; } v; v.f = f;
    unsigned int x = v.i;
    return (unsigned short)((x + 0x7fffu + ((x >> 16) & 1u)) >> 16);
}
static __device__ __forceinline__ void gl2lds16(const void* g, void* l) {
    __builtin_amdgcn_global_load_lds((const AS1 void*)g, (AS3 void*)l, 16, 0, 0);
}

// ---------------- fp32 -> bf16 bulk conversion (RTNE) ----------------
__global__ __launch_bounds__(256)
void conv_f32_bf16(const float* __restrict__ src, unsigned short* __restrict__ dst, int n8)
{
    int i = blockIdx.x * 256 + threadIdx.x;
    if (i >= n8) return;
    const float* p = src + (size_t)i * 8;
    float4 f0 = *(const float4*)p;
    float4 f1 = *(const float4*)(p + 4);
    u16x8 h;
    h[0]=f2bf(f0.x); h[1]=f2bf(f0.y); h[2]=f2bf(f0.z); h[3]=f2bf(f0.w);
    h[4]=f2bf(f1.x); h[5]=f2bf(f1.y); h[6]=f2bf(f1.z); h[7]=f2bf(f1.w);
    *(u16x8*)&dst[(size_t)i * 8] = h;
}

// ---------------- fast GEMM: bf16 A/B, global_load_lds staging (m97 structure) ----------------
// C[M][N] = A[M][K] * Bw[N][K]^T + bias[N]; 128x128 tile, BK=32, 4 waves 2x2, 4x4 MFMA each.
template<bool C_BF16>
__global__ __launch_bounds__(256)
void gemm_bf16_bt(const unsigned short* __restrict__ A,
                  const unsigned short* __restrict__ Bw,
                  const float* __restrict__ bias,
                  void* __restrict__ Cv,
                  int M, int N, int K)
{
    __shared__ unsigned short As[128 * 32];   // unpadded: required by global_load_lds lane order
    __shared__ unsigned short Bs[128 * 32];

    const int tid  = threadIdx.x;
    const int m0   = blockIdx.y * 128;
    const int n0   = blockIdx.x * 128;
    const int wave = tid >> 6, lane = tid & 63;
    const int wm   = (wave >> 1) * 64;
    const int wn   = (wave & 1) * 64;
    const int lm   = lane & 15, quad = lane >> 4;

    f32x4 acc[4][4] = {};

    for (int k0 = 0; k0 < K; k0 += 32) {
        __syncthreads();
        #pragma unroll
        for (int p = 0; p < 2; ++p) {
            int chunk = tid + p * 256;           // 0..511, 16 B each
            int row   = chunk >> 2;
            int off   = (chunk & 3) * 8;
            gl2lds16(&A [(size_t)(m0 + row) * K + k0 + off], &As[chunk * 8]);
            gl2lds16(&Bw[(size_t)(n0 + row) * K + k0 + off], &Bs[chunk * 8]);
        }
        __syncthreads();

        bf16x8 afr[4], bfr[4];
        #pragma unroll
        for (int i = 0; i < 4; ++i)
            afr[i] = *(const bf16x8*)&As[(wm + i * 16 + lm) * 32 + quad * 8];
        #pragma unroll
        for (int j = 0; j < 4; ++j)
            bfr[j] = *(const bf16x8*)&Bs[(wn + j * 16 + lm) * 32 + quad * 8];

        #pragma unroll
        for (int i = 0; i < 4; ++i)
            #pragma unroll
            for (int j = 0; j < 4; ++j)
                acc[i][j] = __builtin_amdgcn_mfma_f32_16x16x32_bf16(afr[i], bfr[j], acc[i][j], 0, 0, 0);
    }

    #pragma unroll
    for (int j = 0; j < 4; ++j) {
        int col = n0 + wn + j * 16 + lm;
        float bv = bias[col];
        #pragma unroll
        for (int i = 0; i < 4; ++i) {
            int rowb = m0 + wm + i * 16 + quad * 4;
            #pragma unroll
            for (int r = 0; r < 4; ++r) {
                float val = acc[i][j][r] + bv;
                if (C_BF16)
                    ((unsigned short*)Cv)[(size_t)(rowb + r) * N + col] = f2bf(val);
                else
                    ((float*)Cv)[(size_t)(rowb + r) * N + col] = val;
            }
        }
    }
}

// ---------------- fallback GEMM (fp32 staging, round-3 proven) ----------------
template<bool A_BF16, bool C_BF16>
__global__ __launch_bounds__(256)
void gemm_bt_bias(const void* __restrict__ Av,
                  const float* __restrict__ Bw,
                  const float* __restrict__ bias,
                  void* __restrict__ Cv,
                  int M, int N, int K)
{
    __shared__ unsigned short As[128 * 40];
    __shared__ unsigned short Bs[128 * 40];

    const int tid  = threadIdx.x;
    const int m0   = blockIdx.y * 128;
    const int n0   = blockIdx.x * 128;
    const int wave = tid >> 6, lane = tid & 63;
    const int wm   = (wave >> 1) * 64;
    const int wn   = (wave & 1) * 64;
    const int lm   = lane & 15, quad = lane >> 4;

    f32x4 acc[4][4] = {};

    for (int k0 = 0; k0 < K; k0 += 32) {
        __syncthreads();
        #pragma unroll
        for (int c = 0; c < 2; ++c) {
            int chunk = tid + c * 256;
            int row   = chunk >> 2;
            int off   = (chunk & 3) * 8;
            if (A_BF16) {
                *(u16x8*)&As[row * 40 + off] =
                    *(const u16x8*)&((const unsigned short*)Av)[(size_t)(m0 + row) * K + k0 + off];
            } else {
                const float* ap = &((const float*)Av)[(size_t)(m0 + row) * K + k0 + off];
                float4 f0 = *(const float4*)ap;
                float4 f1 = *(const float4*)(ap + 4);
                u16x8 h;
                h[0]=f2bf(f0.x); h[1]=f2bf(f0.y); h[2]=f2bf(f0.z); h[3]=f2bf(f0.w);
                h[4]=f2bf(f1.x); h[5]=f2bf(f1.y); h[6]=f2bf(f1.z); h[7]=f2bf(f1.w);
                *(u16x8*)&As[row * 40 + off] = h;
            }
            {
                const float* bp = &Bw[(size_t)(n0 + row) * K + k0 + off];
                float4 f0 = *(const float4*)bp;
                float4 f1 = *(const float4*)(bp + 4);
                u16x8 h;
                h[0]=f2bf(f0.x); h[1]=f2bf(f0.y); h[2]=f2bf(f0.z); h[3]=f2bf(f0.w);
                h[4]=f2bf(f1.x); h[5]=f2bf(f1.y); h[6]=f2bf(f1.z); h[7]=f2bf(f1.w);
                *(u16x8*)&Bs[row * 40 + off] = h;
            }
        }
        __syncthreads();

        bf16x8 afr[4], bfr[4];
        #pragma unroll
        for (int i = 0; i < 4; ++i)
            afr[i] = *(const bf16x8*)&As[(wm + i * 16 + lm) * 40 + quad * 8];
        #pragma unroll
        for (int j = 0; j < 4; ++j)
            bfr[j] = *(const bf16x8*)&Bs[(wn + j * 16 + lm) * 40 + quad * 8];

        #pragma unroll
        for (int i = 0; i < 4; ++i)
            #pragma unroll
            for (int j = 0; j < 4; ++j)
                acc[i][j] = __builtin_amdgcn_mfma_f32_16x16x32_bf16(afr[i], bfr[j], acc[i][j], 0, 0, 0);
    }

    #pragma unroll
    for (int j = 0; j < 4; ++j) {
        int col = n0 + wn + j * 16 + lm;
        float bv = bias[col];
        #pragma unroll
        for (int i = 0; i < 4; ++i) {
            int rowb = m0 + wm + i * 16 + quad * 4;
            #pragma unroll
            for (int r = 0; r < 4; ++r) {
                float val = acc[i][j][r] + bv;
                if (C_BF16)
                    ((unsigned short*)Cv)[(size_t)(rowb + r) * N + col] = f2bf(val);
                else
                    ((float*)Cv)[(size_t)(rowb + r) * N + col] = val;
            }
        }
    }
}

// ---------------- RoPE (in-place on bf16 qkv) ----------------
__global__ __launch_bounds__(256)
void rope_kernel(unsigned short* __restrict__ qkv,
                 const float* __restrict__ cosb,
                 const float* __restrict__ sinb)
{
    int t    = blockIdx.x * 256 + threadIdx.x;
    int d    = t & 63;
    int rest = t >> 6;
    int head = rest % 40;
    int m    = rest / 40;
    int s    = m & (S_ - 1);
    int obase = (head < NH) ? head * D_ : HID + (head - NH) * D_;
    size_t base = (size_t)m * QKV_OUT + obase;

    float x1 = bf2f(qkv[base + d]);
    float x2 = bf2f(qkv[base + d + 64]);
    float c1 = cosb[s * D_ + d];
    float s1 = sinb[s * D_ + d];
    float c2 = cosb[s * D_ + d + 64];
    float s2 = sinb[s * D_ + d + 64];
    qkv[base + d]      = f2bf(x1 * c1 - x2 * s1);
    qkv[base + d + 64] = f2bf(x2 * c2 + x1 * s2);
}

// ---------------- Flash-style MFMA attention (V transposed in LDS) ----------------
__global__ __launch_bounds__(256)
void attn_mfma(const unsigned short* __restrict__ qkv,
               unsigned short* __restrict__ attn)
{
    __shared__ unsigned short Kl[CH * 136];
    __shared__ unsigned short Vt[128 * VSTR];    // [dim][row] transposed
    __shared__ unsigned short Pl[4][16 * 40];

    const int tid  = threadIdx.x;
    const int wave = tid >> 6, lane = tid & 63;
    const int lm   = lane & 15, quad = lane >> 4;
    const int h    = blockIdx.y;
    const int b    = blockIdx.z;
    const int kvh  = h >> 2;
    const int r0b  = blockIdx.x * 64;
    const int rw0  = r0b + wave * 16;

    const size_t qkv_b = (size_t)b * S_ * QKV_OUT;
    const float SCL = 0.12751974f;   // (1/sqrt(128)) * log2(e)

    bf16x8 qf[4];
    {
        const unsigned short* qrow = qkv + qkv_b + (size_t)(rw0 + lm) * QKV_OUT + h * D_ + quad * 8;
        #pragma unroll
        for (int kb = 0; kb < 4; ++kb)
            qf[kb] = *(const bf16x8*)(qrow + kb * 32);
    }

    f32x4 O[8] = {};
    float mrow[4] = {-1e30f, -1e30f, -1e30f, -1e30f};
    float lrow[4] = {0.f, 0.f, 0.f, 0.f};

    const int c0   = max(0, r0b - (WINDOW - 1)) & ~(CH - 1);
    const int cend = r0b + 64 - CH;

    for (int c = c0; c <= cend; c += CH) {
        __syncthreads();
        // K: rows c..c+31, coalesced 16B/lane, padded-136 LDS (conflict-light frag reads)
        #pragma unroll
        for (int p = 0; p < 2; ++p) {
            int idx = tid + p * 256;
            int row = idx >> 4;
            int d0  = (idx & 15) * 8;
            *(u16x8*)&Kl[row * 136 + d0] =
                *(const u16x8*)(qkv + qkv_b + (size_t)(c + row) * QKV_OUT + HID + kvh * D_ + d0);
        }
        // V transposed: thread = 2 rows x 8 dims, packed ds_write_b32 (conflict-free pattern)
        {
            int r2 = (tid & 15) * 2;
            int d0 = (tid >> 4) * 8;
            const unsigned short* vg = qkv + qkv_b + (size_t)(c + r2) * QKV_OUT + HID + NKV * D_ + kvh * D_ + d0;
            u16x8 va = *(const u16x8*)vg;
            u16x8 vb = *(const u16x8*)(vg + QKV_OUT);
            #pragma unroll
            for (int e = 0; e < 8; ++e) {
                unsigned int pack = (unsigned int)va[e] | ((unsigned int)vb[e] << 16);
                *(unsigned int*)&Vt[(d0 + e) * VSTR + r2] = pack;
            }
        }
        __syncthreads();

        if (c + CH - 1 < rw0 - (WINDOW - 1) || c > rw0 + 15) continue;

        // QK^T: two 16-col tiles
        f32x4 s0 = {}, s1 = {};
        #pragma unroll
        for (int kb = 0; kb < 4; ++kb) {
            bf16x8 b0 = *(const bf16x8*)&Kl[lm * 136 + kb * 32 + quad * 8];
            bf16x8 b1 = *(const bf16x8*)&Kl[(16 + lm) * 136 + kb * 32 + quad * 8];
            s0 = __builtin_amdgcn_mfma_f32_16x16x32_bf16(qf[kb], b0, s0, 0, 0, 0);
            s1 = __builtin_amdgcn_mfma_f32_16x16x32_bf16(qf[kb], b1, s1, 0, 0, 0);
        }

        const int j0 = c + lm, j1 = c + 16 + lm;
        float alpha[4];
        #pragma unroll
        for (int r = 0; r < 4; ++r) {
            int row = rw0 + quad * 4 + r;
            float t0 = (j0 <= row && row - j0 < WINDOW) ? s0[r] : -3.0e38f;
            float t1 = (j1 <= row && row - j1 < WINDOW) ? s1[r] : -3.0e38f;
            float cm = fmaxf(t0, t1);
            #pragma unroll
            for (int o = 8; o >= 1; o >>= 1) cm = fmaxf(cm, __shfl_xor(cm, o, 16));
            float mnew = fmaxf(mrow[r], cm);
            float al   = exp2f((mrow[r] - mnew) * SCL);
            float p0   = exp2f((t0 - mnew) * SCL);
            float p1   = exp2f((t1 - mnew) * SCL);
            float rs   = p0 + p1;
            #pragma unroll
            for (int o = 8; o >= 1; o >>= 1) rs += __shfl_xor(rs, o, 16);
            mrow[r] = mnew;
            lrow[r] = lrow[r] * al + rs;
            alpha[r] = al;
            Pl[wave][(quad * 4 + r) * 40 + lm]      = f2bf(p0);
            Pl[wave][(quad * 4 + r) * 40 + 16 + lm] = f2bf(p1);
        }

        #pragma unroll
        for (int nt = 0; nt < 8; ++nt)
            #pragma unroll
            for (int r = 0; r < 4; ++r)
                O[nt][r] *= alpha[r];

        // PV: A = P (wave-private LDS), B = transposed V via ds_read_b128
        bf16x8 pa = *(const bf16x8*)&Pl[wave][lm * 40 + quad * 8];
        #pragma unroll
        for (int nt = 0; nt < 8; ++nt) {
            bf16x8 vbf = *(const bf16x8*)&Vt[(nt * 16 + lm) * VSTR + quad * 8];
            O[nt] = __builtin_amdgcn_mfma_f32_16x16x32_bf16(pa, vbf, O[nt], 0, 0, 0);
        }
    }

    float il[4];
    #pragma unroll
    for (int r = 0; r < 4; ++r) il[r] = 1.0f / lrow[r];
    #pragma unroll
    for (int nt = 0; nt < 8; ++nt)
        #pragma unroll
        for (int r = 0; r < 4; ++r) {
            int row = rw0 + quad * 4 + r;
            attn[(size_t)(b * S_ + row) * (NH * D_) + h * D_ + nt * 16 + lm] = f2bf(O[nt][r] * il[r]);
        }
}

extern "C" void kernel_launch(void* const* d_in, const int* in_sizes, int n_in,
                              void* d_out, int out_size, void* d_ws, size_t ws_size,
                              hipStream_t stream)
{
    const float* hidden = (const float*)d_in[0];
    const float* cosb   = (const float*)d_in[1];
    const float* sinb   = (const float*)d_in[2];
    const float* w_qkv  = (const float*)d_in[3];
    const float* b_qkv  = (const float*)d_in[4];
    const float* w_o    = (const float*)d_in[5];
    const float* b_o    = (const float*)d_in[6];
    float* out = (float*)d_out;

    unsigned char* ws = (unsigned char*)d_ws;
    const size_t QKV_B  = (size_t)M_TOT * QKV_OUT * 2;       // 25.2 MB
    const size_t ATTN_B = (size_t)M_TOT * HID * 2;           // 16.8 MB
    const size_t HB_B   = (size_t)M_TOT * HID * 2;           // 16.8 MB
    const size_t WQ_B   = (size_t)QKV_OUT * HID * 2;         // 50.3 MB
    const size_t WO_B   = (size_t)HID * HID * 2;             // 33.6 MB
    const size_t NEED   = QKV_B + ATTN_B + HB_B + WQ_B;      // wo aliases hb+wq region

    unsigned short* qkv_ws  = (unsigned short*)(ws);
    unsigned short* attn_ws = (unsigned short*)(ws + QKV_B);

    dim3 blk(256);

    if (ws_size >= NEED && WO_B <= HB_B + WQ_B) {
        unsigned short* hb = (unsigned short*)(ws + QKV_B + ATTN_B);
        unsigned short* wq = (unsigned short*)(ws + QKV_B + ATTN_B + HB_B);
        unsigned short* wo = (unsigned short*)(ws + QKV_B + ATTN_B);   // reuse after gemm1

        int n8h = M_TOT * HID / 8;
        int n8q = QKV_OUT * HID / 8;
        int n8o = HID * HID / 8;
        conv_f32_bf16<<<dim3((n8h + 255) / 256), blk, 0, stream>>>(hidden, hb, n8h);
        conv_f32_bf16<<<dim3((n8q + 255) / 256), blk, 0, stream>>>(w_qkv, wq, n8q);
        gemm_bf16_bt<true><<<dim3(QKV_OUT / 128, M_TOT / 128), blk, 0, stream>>>(
            hb, wq, b_qkv, qkv_ws, M_TOT, QKV_OUT, HID);
        rope_kernel<<<dim3((M_TOT * 40 * 64) / 256), blk, 0, stream>>>(qkv_ws, cosb, sinb);
        conv_f32_bf16<<<dim3((n8o + 255) / 256), blk, 0, stream>>>(w_o, wo, n8o);
        attn_mfma<<<dim3(S_ / 64, NH, B_), blk, 0, stream>>>(qkv_ws, attn_ws);
        gemm_bf16_bt<false><<<dim3(HID / 128, M_TOT / 128), blk, 0, stream>>>(
            attn_ws, wo, b_o, out, M_TOT, HID, NH * D_);
    } else {
        gemm_bt_bias<false, true><<<dim3(QKV_OUT / 128, M_TOT / 128), blk, 0, stream>>>(
            hidden, w_qkv, b_qkv, qkv_ws, M_TOT, QKV_OUT, HID);
        rope_kernel<<<dim3((M_TOT * 40 * 64) / 256), blk, 0, stream>>>(qkv_ws, cosb, sinb);
        attn_mfma<<<dim3(S_ / 64, NH, B_), blk, 0, stream>>>(qkv_ws, attn_ws);
        gemm_bt_bias<true, false><<<dim3(HID / 128, M_TOT / 128), blk, 0, stream>>>(
            attn_ws, w_o, b_o, out, M_TOT, HID, NH * D_);
    }
}